// Round 13
// baseline (338.716 us; speedup 1.0000x reference)
//
#include <hip/hip_runtime.h>
#include <hip/hip_bf16.h>

#define BB 4
#define CPG 48
#define HH 128
#define WW2 128
#define PP 16384
#define DIM 384
#define DIM3 1152

typedef unsigned short u16;
typedef __attribute__((ext_vector_type(8))) short bf16x8;
typedef __attribute__((ext_vector_type(4))) float f32x4;

__device__ __forceinline__ float bf2f(u16 u) {
    return __uint_as_float(((unsigned int)u) << 16);
}
__device__ __forceinline__ u16 f2bf(float f) {
    unsigned int u = __float_as_uint(f);
    unsigned int r = (u + 0x7fffu + ((u >> 16) & 1u)) >> 16;
    return (u16)r;
}

// LDS swizzle: rows are 128B; XOR the 16B-slot index with (row&7) to spread banks
__device__ __forceinline__ int swz(int row, int kb) {
    return row * 128 + (kb ^ ((row & 7) << 4));
}

// async global->LDS, 16B per lane; LDS dest = wave-uniform base + lane*16
__device__ __forceinline__ void gld_lds16(const u16* g, char* l) {
    __builtin_amdgcn_global_load_lds(
        (const __attribute__((address_space(1))) void*)g,
        (__attribute__((address_space(3))) void*)l, 16, 0, 0);
}

// ---------------- convert w_qkv fp32 -> bf16
__global__ __launch_bounds__(256) void k_wcvt(const float* __restrict__ w,
                                              u16* __restrict__ wbf)
{
    const int i4 = (blockIdx.x * 256 + threadIdx.x) * 4;
    float4 v = *reinterpret_cast<const float4*>(w + i4);
    ushort4 s;
    s.x = f2bf(v.x); s.y = f2bf(v.y); s.z = f2bf(v.z); s.w = f2bf(v.w);
    *reinterpret_cast<ushort4*>(wbf + i4) = s;
}

// ---------------- transpose x [b][k=384][p] fp32 -> Xt [b][p][k=384] bf16
__global__ __launch_bounds__(256) void k_tr_x(const float* __restrict__ x,
                                              u16* __restrict__ xt)
{
    const int b = blockIdx.z;
    const int k0 = blockIdx.y * 64;
    const int p0 = blockIdx.x * 64;
    const int t = threadIdx.x;
    __shared__ u16 T[64][68];

    const int kl = t >> 4;          // 0..15
    const int pl = (t & 15) * 4;    // 0..60
#pragma unroll
    for (int ks = 0; ks < 4; ++ks) {
        const int k = ks * 16 + kl;
        float4 v = *reinterpret_cast<const float4*>(&x[((size_t)b * DIM + k0 + k) * PP + p0 + pl]);
        ushort4 s;
        s.x = f2bf(v.x); s.y = f2bf(v.y); s.z = f2bf(v.z); s.w = f2bf(v.w);
        *reinterpret_cast<ushort4*>(&T[k][pl]) = s;
    }
    __syncthreads();
    const int pr = t >> 2;          // 0..63
    const int kg = (t & 3) * 16;    // 0,16,32,48
    __align__(16) u16 tmp[16];
#pragma unroll
    for (int j = 0; j < 16; ++j) tmp[j] = T[kg + j][pr];
    u16* dst = xt + ((size_t)b * PP + p0 + pr) * DIM + k0 + kg;
    *reinterpret_cast<uint4*>(dst)     = *reinterpret_cast<uint4*>(tmp);
    *reinterpret_cast<uint4*>(dst + 8) = *reinterpret_cast<uint4*>(tmp + 8);
}

// ---------------- transpose v part of y2 [b][768+c][p] bf16 -> Vt [b][p][c=384] bf16
__global__ __launch_bounds__(256) void k_tr_v(const u16* __restrict__ y2,
                                              u16* __restrict__ vt)
{
    const int b = blockIdx.z;
    const int c0 = blockIdx.y * 64;
    const int p0 = blockIdx.x * 64;
    const int t = threadIdx.x;
    __shared__ u16 T[64][68];

    const int cl = t >> 4;
    const int pl = (t & 15) * 4;
#pragma unroll
    for (int cs = 0; cs < 4; ++cs) {
        const int c = cs * 16 + cl;
        ushort4 v = *reinterpret_cast<const ushort4*>(
            &y2[((size_t)b * DIM3 + 2 * DIM + c0 + c) * PP + p0 + pl]);
        *reinterpret_cast<ushort4*>(&T[c][pl]) = v;
    }
    __syncthreads();
    const int pr = t >> 2;
    const int kg = (t & 3) * 16;
    __align__(16) u16 tmp[16];
#pragma unroll
    for (int j = 0; j < 16; ++j) tmp[j] = T[kg + j][pr];
    u16* dst = vt + ((size_t)b * PP + p0 + pr) * DIM + c0 + kg;
    *reinterpret_cast<uint4*>(dst)     = *reinterpret_cast<uint4*>(tmp);
    *reinterpret_cast<uint4*>(dst + 8) = *reinterpret_cast<uint4*>(tmp + 8);
}

// ---------------- MFMA GEMM: C[b][co][p] = sum_k A[(b)][co][k] * Bt[b][p][k]
// MODE 0: += bias, write bf16 ybf.  MODE 1: += bias + xres, write fp32 fout.
// Staging via global_load_lds(16B) with pre-swizzled per-lane GLOBAL source.
template<int MODE>
__global__ __launch_bounds__(256) void k_gemm(const u16* __restrict__ A, int aStride,
                                              const u16* __restrict__ Bt,
                                              const float* __restrict__ bias,
                                              u16* __restrict__ ybf,
                                              const float* __restrict__ xres,
                                              float* __restrict__ fout,
                                              int nyTiles)
{
    const int bid = blockIdx.x;
    const int xcd = bid & 7;
    const int r1  = bid >> 3;
    const int px  = xcd * 16 + (r1 & 15);   // p-tile 0..127
    const int r2  = r1 >> 4;
    const int b   = r2 / nyTiles;           // batch
    const int yt  = r2 - b * nyTiles;       // co-tile
    const int co0 = yt * 128;
    const int p0  = px * 128;

    const int t   = threadIdx.x;
    const int l   = t & 63;
    const int wid = t >> 6;
    const int wr  = wid >> 1;      // 0..1 -> row half
    const int wc  = wid & 1;       // 0..1 -> col half
    const int lr  = l & 15;
    const int lg  = l >> 4;        // 0..3

    __shared__ __align__(16) char lds[32768];
    char* AsB = lds;               // [128 rows][64 k] bf16, swizzled content
    char* BsB = lds + 16384;

    f32x4 acc[4][4];
#pragma unroll
    for (int m = 0; m < 4; ++m)
#pragma unroll
        for (int n = 0; n < 4; ++n) acc[m][n] = (f32x4){0.f, 0.f, 0.f, 0.f};

    const u16* Ab  = A  + (size_t)b * aStride;
    const u16* Btb = Bt + (size_t)b * PP * DIM;

    // per-lane source mapping for gld_lds16 (8 rows / wave-issue)
    const int lrow8 = l >> 3;                 // 0..7 within the 8-row group
    const int sl    = l & 7;                  // 16B slot 0..7 within 128B row

    for (int k0 = 0; k0 < DIM; k0 += 64) {
        if (k0) __syncthreads();   // prev iter's LDS reads complete
#pragma unroll
        for (int i = 0; i < 4; ++i) {
            const int rbase = wid * 32 + i * 8;
            const int row   = rbase + lrow8;
            const int elem  = (sl * 8) ^ ((row & 7) << 3);   // inverse swizzle
            gld_lds16(Ab  + (size_t)(co0 + row) * DIM + k0 + elem, AsB + rbase * 128);
            gld_lds16(Btb + (size_t)(p0  + row) * DIM + k0 + elem, BsB + rbase * 128);
        }
        __syncthreads();           // drains vmcnt(0) then barrier -> tiles ready

#pragma unroll
        for (int kk = 0; kk < 64; kk += 32) {
            const int kbyte = kk * 2 + lg * 16;
            bf16x8 av[4], bv[4];
#pragma unroll
            for (int m = 0; m < 4; ++m) {
                const int row = wr * 64 + m * 16 + lr;
                av[m] = *reinterpret_cast<const bf16x8*>(AsB + swz(row, kbyte));
            }
#pragma unroll
            for (int n = 0; n < 4; ++n) {
                const int row = wc * 64 + n * 16 + lr;
                bv[n] = *reinterpret_cast<const bf16x8*>(BsB + swz(row, kbyte));
            }
#pragma unroll
            for (int m = 0; m < 4; ++m)
#pragma unroll
                for (int n = 0; n < 4; ++n)
                    acc[m][n] = __builtin_amdgcn_mfma_f32_16x16x32_bf16(
                        av[m], bv[n], acc[m][n], 0, 0, 0);
        }
    }

    // bias per (m, r): row = wr*64 + m*16 + lg*4 + r
    float bias_r[4][4];
#pragma unroll
    for (int m = 0; m < 4; ++m)
#pragma unroll
        for (int r = 0; r < 4; ++r)
            bias_r[m][r] = bias[co0 + wr * 64 + m * 16 + lg * 4 + r];

    if (MODE == 0) {
        __syncthreads();
        u16* Cs = reinterpret_cast<u16*>(lds);
#pragma unroll
        for (int m = 0; m < 4; ++m)
#pragma unroll
            for (int n = 0; n < 4; ++n)
#pragma unroll
                for (int r = 0; r < 4; ++r) {
                    const int row = wr * 64 + m * 16 + lg * 4 + r;
                    const int col = wc * 64 + n * 16 + lr;
                    Cs[row * 128 + col] = f2bf(acc[m][n][r] + bias_r[m][r]);
                }
        __syncthreads();
        // coalesced store: 16 lanes cover one 256B row segment
        const int rr = t >> 4;          // 0..15
        const int cs = (t & 15) * 8;    // u16 col
#pragma unroll
        for (int j = 0; j < 8; ++j) {
            const int row = j * 16 + rr;
            *reinterpret_cast<uint4*>(&ybf[((size_t)b * DIM3 + co0 + row) * PP + p0 + cs]) =
                *reinterpret_cast<const uint4*>(&Cs[row * 128 + cs]);
        }
    } else {
        // fp32 epilogue via LDS in two 64-row half-passes
        float* Cf = reinterpret_cast<float*>(lds);
#pragma unroll
        for (int h = 0; h < 2; ++h) {
            __syncthreads();
            if (wr == h) {
#pragma unroll
                for (int m = 0; m < 4; ++m)
#pragma unroll
                    for (int n = 0; n < 4; ++n)
#pragma unroll
                        for (int r = 0; r < 4; ++r) {
                            const int lrow = m * 16 + lg * 4 + r;
                            const int col = wc * 64 + n * 16 + lr;
                            Cf[lrow * 128 + col] = acc[m][n][r] + bias_r[m][r];
                        }
            }
            __syncthreads();
            const int rr = t >> 5;          // 0..7
            const int cc = (t & 31) * 4;    // fp32 col
#pragma unroll
            for (int j = 0; j < 8; ++j) {
                const int lrow = j * 8 + rr;
                const int grow = h * 64 + lrow;
                const size_t idx = ((size_t)b * DIM + co0 + grow) * PP + p0 + cc;
                float4 xr = *reinterpret_cast<const float4*>(&xres[idx]);
                float4 cv = *reinterpret_cast<const float4*>(&Cf[lrow * 128 + cc]);
                cv.x += xr.x; cv.y += xr.y; cv.z += xr.z; cv.w += xr.w;
                *reinterpret_cast<float4*>(&fout[idx]) = cv;
            }
        }
    }
}

// ---------------- depthwise 3x3 for V channels only -> bf16 y2 (v range)
#define LOADROW(arr, r)                                                        \
    {                                                                          \
        const int r_ = (r);                                                    \
        if (r_ >= 0 && r_ < HH) {                                              \
            union { int4 v; u16 u[8]; } cc_;                                   \
            cc_.v = *reinterpret_cast<const int4*>(img + r_ * WW2 + c0);       \
            arr[1] = bf2f(cc_.u[0]); arr[2] = bf2f(cc_.u[1]);                  \
            arr[3] = bf2f(cc_.u[2]); arr[4] = bf2f(cc_.u[3]);                  \
            arr[5] = bf2f(cc_.u[4]); arr[6] = bf2f(cc_.u[5]);                  \
            arr[7] = bf2f(cc_.u[6]); arr[8] = bf2f(cc_.u[7]);                  \
        } else {                                                               \
            arr[1] = 0.f; arr[2] = 0.f; arr[3] = 0.f; arr[4] = 0.f;            \
            arr[5] = 0.f; arr[6] = 0.f; arr[7] = 0.f; arr[8] = 0.f;            \
        }                                                                      \
        float lf_ = __shfl(arr[8], t - 1);                                     \
        float rt_ = __shfl(arr[1], t + 1);                                     \
        arr[0] = (tc > 0)  ? lf_ : 0.f;                                        \
        arr[9] = (tc < 15) ? rt_ : 0.f;                                        \
    }

__global__ __launch_bounds__(256) void k_dwv(const u16* __restrict__ y1,
                                             const float* __restrict__ wdw,
                                             const float* __restrict__ bdw,
                                             u16* __restrict__ y2)
{
    const int ch = 2 * DIM + blockIdx.x;   // v channels 768..1151
    const int b  = blockIdx.y;
    const size_t ib = ((size_t)b * DIM3 + ch) * PP;
    const u16* img = y1 + ib;

    const int t  = (int)threadIdx.x;
    const int tc = t & 15;
    const int tr = t >> 4;
    const int c0 = tc * 8;
    const int r0 = tr * 8;

    float w9[9];
#pragma unroll
    for (int i = 0; i < 9; ++i) w9[i] = wdw[ch * 9 + i];
    const float bv = bdw[ch];

    float A[10], B[10], C[10];
    LOADROW(A, r0 - 1);
    LOADROW(B, r0);

#pragma unroll
    for (int j = 0; j < 8; ++j) {
        LOADROW(C, r0 + j + 1);
        union { int4 v; u16 u[8]; } ou;
#pragma unroll
        for (int c = 0; c < 8; ++c) {
            float a = bv;
            a = fmaf(w9[0], A[c],     a);
            a = fmaf(w9[1], A[c + 1], a);
            a = fmaf(w9[2], A[c + 2], a);
            a = fmaf(w9[3], B[c],     a);
            a = fmaf(w9[4], B[c + 1], a);
            a = fmaf(w9[5], B[c + 2], a);
            a = fmaf(w9[6], C[c],     a);
            a = fmaf(w9[7], C[c + 1], a);
            a = fmaf(w9[8], C[c + 2], a);
            ou.u[c] = f2bf(a);
        }
        *reinterpret_cast<int4*>(y2 + ib + (r0 + j) * WW2 + c0) = ou.v;
#pragma unroll
        for (int q = 0; q < 10; ++q) { A[q] = B[q]; B[q] = C[q]; }
    }
}

// ---------------- fused dw(q,k) + Gram partials. Block = (c, 8-row band, b).
// Stages 16 channel-rows (+halo) in LDS, dw in registers (fp32, never stored),
// thread-local q.k products -> 80 partials per block. No q/k HBM output.
__global__ __launch_bounds__(256) void k_dwqk(const u16* __restrict__ y1,
                                              const float* __restrict__ wdw,
                                              const float* __restrict__ bdw,
                                              float* __restrict__ partial)
{
    const int c    = blockIdx.x;   // 0..47
    const int band = blockIdx.y;   // 0..15
    const int b    = blockIdx.z;   // 0..3
    const int t    = (int)threadIdx.x;
    const int r0   = band * 8;

    // px p lives at u16 index p+2; [0..1] and [130..131] are zero pads
    __shared__ __align__(16) u16 stage[16][10][132];   // 42240 B

    if (t < 160) {
        const int ch = t / 10, row = t - ch * 10;
        *reinterpret_cast<unsigned int*>(&stage[ch][row][0])   = 0u;
        *reinterpret_cast<unsigned int*>(&stage[ch][row][130]) = 0u;
    }
    // stage all 16 (q,k) channels: 16 ch x 10 rows x 16 chunks(16B) = 2560
#pragma unroll
    for (int i = 0; i < 10; ++i) {
        const int tau = t + 256 * i;          // 0..2559
        const int ch = tau / 160;             // 0..15
        const int rem = tau - ch * 160;       // 0..159
        const int row = rem >> 4;             // 0..9
        const int chunk = rem & 15;           // 0..15
        const int gr = r0 - 1 + row;
        const int gch = (ch & 7) * CPG + c + ((ch >= 8) ? DIM : 0);
        uint4 v = {0u, 0u, 0u, 0u};
        if (gr >= 0 && gr < HH)
            v = *reinterpret_cast<const uint4*>(
                y1 + ((size_t)b * DIM3 + gch) * PP + gr * WW2 + chunk * 8);
        unsigned int* dst = reinterpret_cast<unsigned int*>(&stage[ch][row][2 + chunk * 8]);
        dst[0] = v.x; dst[1] = v.y; dst[2] = v.z; dst[3] = v.w;
    }
    __syncthreads();

    const int rr = t >> 5;          // out-row within band 0..7
    const int c4 = (t & 31) * 4;    // 4 px per thread

    float qk[64], qq[8], kk2[8], qreg[8][4];
#pragma unroll
    for (int i = 0; i < 64; ++i) qk[i] = 0.f;
#pragma unroll
    for (int i = 0; i < 8; ++i) { qq[i] = 0.f; kk2[i] = 0.f; }

#pragma unroll
    for (int ch = 0; ch < 16; ++ch) {
        const int gch = (ch & 7) * CPG + c + ((ch >= 8) ? DIM : 0);
        float w9[9];
#pragma unroll
        for (int i = 0; i < 9; ++i) w9[i] = wdw[gch * 9 + i];
        const float bv = bdw[gch];
        float W[3][8];
#pragma unroll
        for (int dr = 0; dr < 3; ++dr)
#pragma unroll
            for (int j = 0; j < 4; ++j) {
                const unsigned int u = *reinterpret_cast<const unsigned int*>(
                    &stage[ch][rr + dr][c4 + j * 2]);
                W[dr][j * 2]     = __uint_as_float(u << 16);
                W[dr][j * 2 + 1] = __uint_as_float(u & 0xffff0000u);
            }
        float dv[4];
#pragma unroll
        for (int i = 0; i < 4; ++i) {
            float a = bv;
#pragma unroll
            for (int dr = 0; dr < 3; ++dr)
#pragma unroll
                for (int dx = 0; dx < 3; ++dx)
                    a = fmaf(w9[dr * 3 + dx], W[dr][1 + i + dx], a);
            dv[i] = a;
        }
        if (ch < 8) {
#pragma unroll
            for (int i = 0; i < 4; ++i) {
                qreg[ch][i] = dv[i];
                qq[ch] = fmaf(dv[i], dv[i], qq[ch]);
            }
        } else {
            const int m = ch - 8;
#pragma unroll
            for (int i = 0; i < 4; ++i) kk2[m] = fmaf(dv[i], dv[i], kk2[m]);
#pragma unroll
            for (int n = 0; n < 8; ++n)
#pragma unroll
                for (int i = 0; i < 4; ++i)
                    qk[n * 8 + m] = fmaf(qreg[n][i], dv[i], qk[n * 8 + m]);
        }
    }

    __syncthreads();   // stage reads done; reuse LDS for cross-wave reduce
    float* red = reinterpret_cast<float*>(stage);
    const int wave = t >> 6, lane = t & 63;
#pragma unroll
    for (int i = 0; i < 80; ++i) {
        float v = (i < 64) ? qk[i] : ((i < 72) ? qq[i - 64] : kk2[i - 72]);
        v += __shfl_down(v, 32); v += __shfl_down(v, 16); v += __shfl_down(v, 8);
        v += __shfl_down(v, 4);  v += __shfl_down(v, 2);  v += __shfl_down(v, 1);
        if (lane == 0) red[wave * 80 + i] = v;
    }
    __syncthreads();
    if (t < 80) {
        const float s = red[t] + red[80 + t] + red[160 + t] + red[240 + t];
        partial[((size_t)((b * 48 + c) * 16 + band)) * 80 + t] = s;
    }
}

// ---------------- reduce partials (768 rows/b), normalize, softmax -> attn[b][8][8]
__global__ __launch_bounds__(256) void k_attn(const float* __restrict__ partial,
                                              const float* __restrict__ temp,
                                              float* __restrict__ attn)
{
    const int b = blockIdx.x;
    const int t = threadIdx.x;
    __shared__ float red3[240];
    __shared__ float dots[80];
    __shared__ float sc[8][8];
    if (t < 240) {
        const int v = t % 80, g = t / 80;
        float s = 0.f;
        for (int i = g * 256; i < g * 256 + 256; ++i)
            s += partial[((size_t)b * 768 + i) * 80 + v];
        red3[t] = s;
    }
    __syncthreads();
    if (t < 80) dots[t] = red3[t] + red3[80 + t] + red3[160 + t];
    __syncthreads();
    if (t < 64) {
        const int n = t >> 3, m = t & 7;
        const float qn = fmaxf(sqrtf(dots[64 + n]), 1e-12f);
        const float km = fmaxf(sqrtf(dots[72 + m]), 1e-12f);
        sc[n][m] = dots[n * 8 + m] / (qn * km) * temp[0];
    }
    __syncthreads();
    if (t < 8) {
        float mx = -3.0e38f;
#pragma unroll
        for (int m = 0; m < 8; ++m) mx = fmaxf(mx, sc[t][m]);
        float e[8], s = 0.f;
#pragma unroll
        for (int m = 0; m < 8; ++m) { e[m] = expf(sc[t][m] - mx); s += e[m]; }
        const float inv = 1.f / s;
#pragma unroll
        for (int m = 0; m < 8; ++m) attn[(b * 8 + t) * 8 + m] = e[m] * inv;
    }
}

// ---------------- Weff[b][co][m*48+c] = sum_n wproj[co][n*48+c]*attn[n][m]  (bf16 out)
__global__ __launch_bounds__(128) void k_weff(const float* __restrict__ attn,
                                              const float* __restrict__ wproj,
                                              u16* __restrict__ weff)
{
    const int b  = blockIdx.y;
    const int co = blockIdx.x;
    const int t  = threadIdx.x;
    __shared__ float a[64];
    if (t < 64) a[t] = attn[b * 64 + t];
    __syncthreads();
    const float* wrow = wproj + (size_t)co * DIM;
    u16* wout = weff + ((size_t)b * DIM + co) * DIM;
    for (int i = t; i < DIM; i += 128) {
        const int m = i / CPG;
        const int c = i - m * CPG;
        float s = 0.f;
#pragma unroll
        for (int n = 0; n < 8; ++n) s += wrow[n * CPG + c] * a[n * 8 + m];
        wout[i] = f2bf(s);
    }
}

extern "C" void kernel_launch(void* const* d_in, const int* in_sizes, int n_in,
                              void* d_out, int out_size, void* d_ws, size_t ws_size,
                              hipStream_t stream)
{
    const float* x      = (const float*)d_in[0];
    const float* temp   = (const float*)d_in[1];
    const float* w_qkv  = (const float*)d_in[2];
    const float* b_qkv  = (const float*)d_in[3];
    const float* w_dw   = (const float*)d_in[4];
    const float* b_dw   = (const float*)d_in[5];
    const float* w_proj = (const float*)d_in[6];
    const float* b_proj = (const float*)d_in[7];
    float* out = (float*)d_out;

    char* ws = (char*)d_ws;
    const size_t SZ_QKV = (size_t)BB * DIM3 * PP * sizeof(u16);  // 150,994,944
    const size_t SZ_XT  = (size_t)BB * PP * DIM * sizeof(u16);   //  50,331,648

    // region 0: [0, SZ_QKV) -- y1 (gemm0 out, read by k_dwv/k_dwqk, then dead)
    u16* y1 = (u16*)ws;
    u16* vt = (u16*)(ws + 4194304);               // 50.3 MB; y1 dead before tr_v

    // region 1: [SZ_QKV, 2*SZ_QKV)
    u16* y2  = (u16*)(ws + SZ_QKV);               // v channels only (>=25.2 MB in)
    u16* xt  = (u16*)(ws + SZ_QKV);               // pre-dw only (dead after gemm0)
    u16* wbf = (u16*)(ws + SZ_QKV + SZ_XT);       // 884,736 B (pre-dw only)
    // small buffers live in the xt-dead / y2-qk-unused space [0, 25 MB):
    float* partial = (float*)(ws + SZ_QKV);              // 983,040 B
    float* attn    = (float*)(ws + SZ_QKV + 983040);     // 1,024 B
    u16*   weffb   = (u16*)(ws + SZ_QKV + 1048576);      // 1,179,648 B

    k_wcvt<<<dim3(DIM3 * DIM / 1024), 256, 0, stream>>>(w_qkv, wbf);
    k_tr_x<<<dim3(PP / 64, DIM / 64, BB), 256, 0, stream>>>(x, xt);
    k_gemm<0><<<dim3(128 * 9 * BB), 256, 0, stream>>>(
        wbf, 0, xt, b_qkv, y1, nullptr, nullptr, 9);
    k_dwv<<<dim3(DIM, BB), 256, 0, stream>>>(y1, w_dw, b_dw, y2);
    k_dwqk<<<dim3(48, 16, BB), 256, 0, stream>>>(y1, w_dw, b_dw, partial);
    k_attn<<<dim3(BB), 256, 0, stream>>>(partial, temp, attn);
    k_weff<<<dim3(DIM, BB), 128, 0, stream>>>(attn, w_proj, weffb);
    k_tr_v<<<dim3(PP / 64, DIM / 64, BB), 256, 0, stream>>>(y2, vt);
    k_gemm<1><<<dim3(128 * 3 * BB), 256, 0, stream>>>(
        weffb, DIM * DIM, vt, b_proj, nullptr, x, out, 3);
}

// Round 14
// 272.802 us; speedup vs baseline: 1.2416x; 1.2416x over previous
//
#include <hip/hip_runtime.h>
#include <hip/hip_bf16.h>

#define BB 4
#define CPG 48
#define HH 128
#define WW2 128
#define PP 16384
#define DIM 384
#define DIM3 1152

typedef unsigned short u16;
typedef __attribute__((ext_vector_type(8))) short bf16x8;
typedef __attribute__((ext_vector_type(4))) float f32x4;

__device__ __forceinline__ float bf2f(u16 u) {
    return __uint_as_float(((unsigned int)u) << 16);
}
__device__ __forceinline__ u16 f2bf(float f) {
    unsigned int u = __float_as_uint(f);
    unsigned int r = (u + 0x7fffu + ((u >> 16) & 1u)) >> 16;
    return (u16)r;
}

// LDS swizzle: rows are 128B; XOR the 16B-slot index with (row&7) to spread banks
__device__ __forceinline__ int swz(int row, int kb) {
    return row * 128 + (kb ^ ((row & 7) << 4));
}

// async global->LDS, 16B per lane; LDS dest = wave-uniform base + lane*16
__device__ __forceinline__ void gld_lds16(const u16* g, char* l) {
    __builtin_amdgcn_global_load_lds(
        (const __attribute__((address_space(1))) void*)g,
        (__attribute__((address_space(3))) void*)l, 16, 0, 0);
}

// ---------------- convert w_qkv fp32 -> bf16
__global__ __launch_bounds__(256) void k_wcvt(const float* __restrict__ w,
                                              u16* __restrict__ wbf)
{
    const int i4 = (blockIdx.x * 256 + threadIdx.x) * 4;
    float4 v = *reinterpret_cast<const float4*>(w + i4);
    ushort4 s;
    s.x = f2bf(v.x); s.y = f2bf(v.y); s.z = f2bf(v.z); s.w = f2bf(v.w);
    *reinterpret_cast<ushort4*>(wbf + i4) = s;
}

// ---------------- transpose x [b][k=384][p] fp32 -> Xt [b][p][k=384] bf16
__global__ __launch_bounds__(256) void k_tr_x(const float* __restrict__ x,
                                              u16* __restrict__ xt)
{
    const int b = blockIdx.z;
    const int k0 = blockIdx.y * 64;
    const int p0 = blockIdx.x * 64;
    const int t = threadIdx.x;
    __shared__ u16 T[64][68];

    const int kl = t >> 4;          // 0..15
    const int pl = (t & 15) * 4;    // 0..60
#pragma unroll
    for (int ks = 0; ks < 4; ++ks) {
        const int k = ks * 16 + kl;
        float4 v = *reinterpret_cast<const float4*>(&x[((size_t)b * DIM + k0 + k) * PP + p0 + pl]);
        ushort4 s;
        s.x = f2bf(v.x); s.y = f2bf(v.y); s.z = f2bf(v.z); s.w = f2bf(v.w);
        *reinterpret_cast<ushort4*>(&T[k][pl]) = s;
    }
    __syncthreads();
    const int pr = t >> 2;          // 0..63
    const int kg = (t & 3) * 16;    // 0,16,32,48
    __align__(16) u16 tmp[16];
#pragma unroll
    for (int j = 0; j < 16; ++j) tmp[j] = T[kg + j][pr];
    u16* dst = xt + ((size_t)b * PP + p0 + pr) * DIM + k0 + kg;
    *reinterpret_cast<uint4*>(dst)     = *reinterpret_cast<uint4*>(tmp);
    *reinterpret_cast<uint4*>(dst + 8) = *reinterpret_cast<uint4*>(tmp + 8);
}

// ---------------- transpose v part of y2 [b][768+c][p] bf16 -> Vt [b][p][c=384] bf16
__global__ __launch_bounds__(256) void k_tr_v(const u16* __restrict__ y2,
                                              u16* __restrict__ vt)
{
    const int b = blockIdx.z;
    const int c0 = blockIdx.y * 64;
    const int p0 = blockIdx.x * 64;
    const int t = threadIdx.x;
    __shared__ u16 T[64][68];

    const int cl = t >> 4;
    const int pl = (t & 15) * 4;
#pragma unroll
    for (int cs = 0; cs < 4; ++cs) {
        const int c = cs * 16 + cl;
        ushort4 v = *reinterpret_cast<const ushort4*>(
            &y2[((size_t)b * DIM3 + 2 * DIM + c0 + c) * PP + p0 + pl]);
        *reinterpret_cast<ushort4*>(&T[c][pl]) = v;
    }
    __syncthreads();
    const int pr = t >> 2;
    const int kg = (t & 3) * 16;
    __align__(16) u16 tmp[16];
#pragma unroll
    for (int j = 0; j < 16; ++j) tmp[j] = T[kg + j][pr];
    u16* dst = vt + ((size_t)b * PP + p0 + pr) * DIM + c0 + kg;
    *reinterpret_cast<uint4*>(dst)     = *reinterpret_cast<uint4*>(tmp);
    *reinterpret_cast<uint4*>(dst + 8) = *reinterpret_cast<uint4*>(tmp + 8);
}

// ---------------- MFMA GEMM: C[b][co][p] = sum_k A[(b)][co][k] * Bt[b][p][k]
// MODE 0: += bias, write bf16 ybf.  MODE 1: += bias + xres, write fp32 fout.
// Staging via global_load_lds(16B) with pre-swizzled per-lane GLOBAL source.
template<int MODE>
__global__ __launch_bounds__(256) void k_gemm(const u16* __restrict__ A, int aStride,
                                              const u16* __restrict__ Bt,
                                              const float* __restrict__ bias,
                                              u16* __restrict__ ybf,
                                              const float* __restrict__ xres,
                                              float* __restrict__ fout,
                                              int nyTiles)
{
    const int bid = blockIdx.x;
    const int xcd = bid & 7;
    const int r1  = bid >> 3;
    const int px  = xcd * 16 + (r1 & 15);   // p-tile 0..127
    const int r2  = r1 >> 4;
    const int b   = r2 / nyTiles;           // batch
    const int yt  = r2 - b * nyTiles;       // co-tile
    const int co0 = yt * 128;
    const int p0  = px * 128;

    const int t   = threadIdx.x;
    const int l   = t & 63;
    const int wid = t >> 6;
    const int wr  = wid >> 1;      // 0..1 -> row half
    const int wc  = wid & 1;       // 0..1 -> col half
    const int lr  = l & 15;
    const int lg  = l >> 4;        // 0..3

    __shared__ __align__(16) char lds[32768];
    char* AsB = lds;               // [128 rows][64 k] bf16, swizzled content
    char* BsB = lds + 16384;

    f32x4 acc[4][4];
#pragma unroll
    for (int m = 0; m < 4; ++m)
#pragma unroll
        for (int n = 0; n < 4; ++n) acc[m][n] = (f32x4){0.f, 0.f, 0.f, 0.f};

    const u16* Ab  = A  + (size_t)b * aStride;
    const u16* Btb = Bt + (size_t)b * PP * DIM;

    // per-lane source mapping for gld_lds16 (8 rows / wave-issue)
    const int lrow8 = l >> 3;                 // 0..7 within the 8-row group
    const int sl    = l & 7;                  // 16B slot 0..7 within 128B row

    for (int k0 = 0; k0 < DIM; k0 += 64) {
        if (k0) __syncthreads();   // prev iter's LDS reads complete
#pragma unroll
        for (int i = 0; i < 4; ++i) {
            const int rbase = wid * 32 + i * 8;
            const int row   = rbase + lrow8;
            const int elem  = (sl * 8) ^ ((row & 7) << 3);   // inverse swizzle
            gld_lds16(Ab  + (size_t)(co0 + row) * DIM + k0 + elem, AsB + rbase * 128);
            gld_lds16(Btb + (size_t)(p0  + row) * DIM + k0 + elem, BsB + rbase * 128);
        }
        __syncthreads();           // drains vmcnt(0) then barrier -> tiles ready

#pragma unroll
        for (int kk = 0; kk < 64; kk += 32) {
            const int kbyte = kk * 2 + lg * 16;
            bf16x8 av[4], bv[4];
#pragma unroll
            for (int m = 0; m < 4; ++m) {
                const int row = wr * 64 + m * 16 + lr;
                av[m] = *reinterpret_cast<const bf16x8*>(AsB + swz(row, kbyte));
            }
#pragma unroll
            for (int n = 0; n < 4; ++n) {
                const int row = wc * 64 + n * 16 + lr;
                bv[n] = *reinterpret_cast<const bf16x8*>(BsB + swz(row, kbyte));
            }
#pragma unroll
            for (int m = 0; m < 4; ++m)
#pragma unroll
                for (int n = 0; n < 4; ++n)
                    acc[m][n] = __builtin_amdgcn_mfma_f32_16x16x32_bf16(
                        av[m], bv[n], acc[m][n], 0, 0, 0);
        }
    }

    // bias per (m, r): row = wr*64 + m*16 + lg*4 + r
    float bias_r[4][4];
#pragma unroll
    for (int m = 0; m < 4; ++m)
#pragma unroll
        for (int r = 0; r < 4; ++r)
            bias_r[m][r] = bias[co0 + wr * 64 + m * 16 + lg * 4 + r];

    if (MODE == 0) {
        __syncthreads();
        u16* Cs = reinterpret_cast<u16*>(lds);
#pragma unroll
        for (int m = 0; m < 4; ++m)
#pragma unroll
            for (int n = 0; n < 4; ++n)
#pragma unroll
                for (int r = 0; r < 4; ++r) {
                    const int row = wr * 64 + m * 16 + lg * 4 + r;
                    const int col = wc * 64 + n * 16 + lr;
                    Cs[row * 128 + col] = f2bf(acc[m][n][r] + bias_r[m][r]);
                }
        __syncthreads();
        // coalesced store: 16 lanes cover one 256B row segment
        const int rr = t >> 4;          // 0..15
        const int cs = (t & 15) * 8;    // u16 col
#pragma unroll
        for (int j = 0; j < 8; ++j) {
            const int row = j * 16 + rr;
            *reinterpret_cast<uint4*>(&ybf[((size_t)b * DIM3 + co0 + row) * PP + p0 + cs]) =
                *reinterpret_cast<const uint4*>(&Cs[row * 128 + cs]);
        }
    } else {
        // fp32 epilogue via LDS in two 64-row half-passes
        float* Cf = reinterpret_cast<float*>(lds);
#pragma unroll
        for (int h = 0; h < 2; ++h) {
            __syncthreads();
            if (wr == h) {
#pragma unroll
                for (int m = 0; m < 4; ++m)
#pragma unroll
                    for (int n = 0; n < 4; ++n)
#pragma unroll
                        for (int r = 0; r < 4; ++r) {
                            const int lrow = m * 16 + lg * 4 + r;
                            const int col = wc * 64 + n * 16 + lr;
                            Cf[lrow * 128 + col] = acc[m][n][r] + bias_r[m][r];
                        }
            }
            __syncthreads();
            const int rr = t >> 5;          // 0..7
            const int cc = (t & 31) * 4;    // fp32 col
#pragma unroll
            for (int j = 0; j < 8; ++j) {
                const int lrow = j * 8 + rr;
                const int grow = h * 64 + lrow;
                const size_t idx = ((size_t)b * DIM + co0 + grow) * PP + p0 + cc;
                float4 xr = *reinterpret_cast<const float4*>(&xres[idx]);
                float4 cv = *reinterpret_cast<const float4*>(&Cf[lrow * 128 + cc]);
                cv.x += xr.x; cv.y += xr.y; cv.z += xr.z; cv.w += xr.w;
                *reinterpret_cast<float4*>(&fout[idx]) = cv;
            }
        }
    }
}

// ---------------- depthwise 3x3 for V channels only -> bf16 y2 (v range)
#define LOADROW(arr, r)                                                        \
    {                                                                          \
        const int r_ = (r);                                                    \
        if (r_ >= 0 && r_ < HH) {                                              \
            union { int4 v; u16 u[8]; } cc_;                                   \
            cc_.v = *reinterpret_cast<const int4*>(img + r_ * WW2 + c0);       \
            arr[1] = bf2f(cc_.u[0]); arr[2] = bf2f(cc_.u[1]);                  \
            arr[3] = bf2f(cc_.u[2]); arr[4] = bf2f(cc_.u[3]);                  \
            arr[5] = bf2f(cc_.u[4]); arr[6] = bf2f(cc_.u[5]);                  \
            arr[7] = bf2f(cc_.u[6]); arr[8] = bf2f(cc_.u[7]);                  \
        } else {                                                               \
            arr[1] = 0.f; arr[2] = 0.f; arr[3] = 0.f; arr[4] = 0.f;            \
            arr[5] = 0.f; arr[6] = 0.f; arr[7] = 0.f; arr[8] = 0.f;            \
        }                                                                      \
        float lf_ = __shfl(arr[8], t - 1);                                     \
        float rt_ = __shfl(arr[1], t + 1);                                     \
        arr[0] = (tc > 0)  ? lf_ : 0.f;                                        \
        arr[9] = (tc < 15) ? rt_ : 0.f;                                        \
    }

__global__ __launch_bounds__(256) void k_dwv(const u16* __restrict__ y1,
                                             const float* __restrict__ wdw,
                                             const float* __restrict__ bdw,
                                             u16* __restrict__ y2)
{
    const int ch = 2 * DIM + blockIdx.x;   // v channels 768..1151
    const int b  = blockIdx.y;
    const size_t ib = ((size_t)b * DIM3 + ch) * PP;
    const u16* img = y1 + ib;

    const int t  = (int)threadIdx.x;
    const int tc = t & 15;
    const int tr = t >> 4;
    const int c0 = tc * 8;
    const int r0 = tr * 8;

    float w9[9];
#pragma unroll
    for (int i = 0; i < 9; ++i) w9[i] = wdw[ch * 9 + i];
    const float bv = bdw[ch];

    float A[10], B[10], C[10];
    LOADROW(A, r0 - 1);
    LOADROW(B, r0);

#pragma unroll
    for (int j = 0; j < 8; ++j) {
        LOADROW(C, r0 + j + 1);
        union { int4 v; u16 u[8]; } ou;
#pragma unroll
        for (int c = 0; c < 8; ++c) {
            float a = bv;
            a = fmaf(w9[0], A[c],     a);
            a = fmaf(w9[1], A[c + 1], a);
            a = fmaf(w9[2], A[c + 2], a);
            a = fmaf(w9[3], B[c],     a);
            a = fmaf(w9[4], B[c + 1], a);
            a = fmaf(w9[5], B[c + 2], a);
            a = fmaf(w9[6], C[c],     a);
            a = fmaf(w9[7], C[c + 1], a);
            a = fmaf(w9[8], C[c + 2], a);
            ou.u[c] = f2bf(a);
        }
        *reinterpret_cast<int4*>(y2 + ib + (r0 + j) * WW2 + c0) = ou.v;
#pragma unroll
        for (int q = 0; q < 10; ++q) { A[q] = B[q]; B[q] = C[q]; }
    }
}

// halo load for k_dwqk: 8 px strip on one row, shuffles for column halo
#define LOADROW2(arr, gr_)                                                     \
    {                                                                          \
        const int r_ = (gr_);                                                  \
        if (r_ >= 0 && r_ < HH) {                                              \
            union { uint4 v; u16 u[8]; } cc_;                                  \
            cc_.v = *reinterpret_cast<const uint4*>(img + r_ * WW2 + sp);      \
            arr[1] = bf2f(cc_.u[0]); arr[2] = bf2f(cc_.u[1]);                  \
            arr[3] = bf2f(cc_.u[2]); arr[4] = bf2f(cc_.u[3]);                  \
            arr[5] = bf2f(cc_.u[4]); arr[6] = bf2f(cc_.u[5]);                  \
            arr[7] = bf2f(cc_.u[6]); arr[8] = bf2f(cc_.u[7]);                  \
        } else {                                                               \
            arr[1] = 0.f; arr[2] = 0.f; arr[3] = 0.f; arr[4] = 0.f;            \
            arr[5] = 0.f; arr[6] = 0.f; arr[7] = 0.f; arr[8] = 0.f;            \
        }                                                                      \
        float lf_ = __shfl(arr[8], t - 1);                                     \
        float rt_ = __shfl(arr[1], t + 1);                                     \
        arr[0] = (s > 0)  ? lf_ : 0.f;                                         \
        arr[9] = (s < 15) ? rt_ : 0.f;                                         \
    }

// ---------------- fused dw(q,k) + MFMA self-Gram. Block = (c, band of 8 rows, b).
// dw phase: 2 sets (q/k, wave-uniform) x 8 rows x 16 strips; dv -> bf16 G[16][1024].
// Gram: S = G*G^T via mfma_f32_16x16x32_bf16, A-frag == B-frag (self-product).
__global__ __launch_bounds__(256) void k_dwqk(const u16* __restrict__ y1,
                                              const float* __restrict__ wdw,
                                              const float* __restrict__ bdw,
                                              float* __restrict__ partial)
{
    const int c    = blockIdx.x;   // 0..47
    const int band = blockIdx.y;   // 0..15
    const int b    = blockIdx.z;   // 0..3
    const int t    = (int)threadIdx.x;
    const int h    = t >> 7;       // 0=q set, 1=k set (wave-uniform)
    const int r    = (t >> 4) & 7; // row within band
    const int s    = t & 15;       // 8-px strip
    const int sp   = s * 8;
    const int r0   = band * 8;

    __shared__ __align__(16) u16 G[16][1032];    // 16 x (1024 + 8 pad) bf16 = 33KB
    __shared__ __align__(16) float red[4][256];  // 4KB

#pragma unroll
    for (int n = 0; n < 8; ++n) {
        const int gch = h * DIM + n * CPG + c;
        const u16* img = y1 + ((size_t)b * DIM3 + gch) * PP;
        float w9[9];
#pragma unroll
        for (int i = 0; i < 9; ++i) w9[i] = wdw[gch * 9 + i];
        const float bv = bdw[gch];

        float A[10], B[10], C[10];
        LOADROW2(A, r0 + r - 1);
        LOADROW2(B, r0 + r);
        LOADROW2(C, r0 + r + 1);

        union { uint4 v; u16 u[8]; } og;
#pragma unroll
        for (int j = 0; j < 8; ++j) {
            float a = bv;
            a = fmaf(w9[0], A[j],     a);
            a = fmaf(w9[1], A[j + 1], a);
            a = fmaf(w9[2], A[j + 2], a);
            a = fmaf(w9[3], B[j],     a);
            a = fmaf(w9[4], B[j + 1], a);
            a = fmaf(w9[5], B[j + 2], a);
            a = fmaf(w9[6], C[j],     a);
            a = fmaf(w9[7], C[j + 1], a);
            a = fmaf(w9[8], C[j + 2], a);
            og.u[j] = f2bf(a);
        }
        *reinterpret_cast<uint4*>(&G[h * 8 + n][r * 128 + sp]) = og.v;
    }
    __syncthreads();

    // Gram: wave w covers K range [w*256, w*256+256)
    const int l = t & 63, w = t >> 6;
    const int grow = l & 15;
    const int koc  = (l >> 4) * 8;
    f32x4 acc = (f32x4){0.f, 0.f, 0.f, 0.f};
#pragma unroll
    for (int q8 = 0; q8 < 8; ++q8) {
        const int koff = w * 256 + q8 * 32 + koc;
        bf16x8 g = *reinterpret_cast<const bf16x8*>(&G[grow][koff]);
        acc = __builtin_amdgcn_mfma_f32_16x16x32_bf16(g, g, acc, 0, 0, 0);
    }
    // C/D layout: col = lane&15, row = (lane>>4)*4 + reg  ->  S[row][col]
#pragma unroll
    for (int rg = 0; rg < 4; ++rg)
        red[w][((l >> 4) * 4 + rg) * 16 + (l & 15)] = acc[rg];
    __syncthreads();

    const float sum = red[0][t] + red[1][t] + red[2][t] + red[3][t];
    partial[((size_t)((b * 48 + c) * 16 + band)) * 256 + t] = sum;
}

// ---------------- reduce partials (768 rows x 256 / b), normalize, softmax -> attn
__global__ __launch_bounds__(256) void k_attn(const float* __restrict__ partial,
                                              const float* __restrict__ temp,
                                              float* __restrict__ attn)
{
    const int b = blockIdx.x;
    const int t = threadIdx.x;
    __shared__ float S[256];
    __shared__ float sc[8][8];
    float s = 0.f;
    for (int i = 0; i < 768; ++i)
        s += partial[((size_t)b * 768 + i) * 256 + t];
    S[t] = s;
    __syncthreads();
    if (t < 64) {
        const int n = t >> 3, m = t & 7;
        const float qn = fmaxf(sqrtf(S[n * 16 + n]), 1e-12f);
        const float km = fmaxf(sqrtf(S[(8 + m) * 16 + 8 + m]), 1e-12f);
        sc[n][m] = S[n * 16 + 8 + m] / (qn * km) * temp[0];
    }
    __syncthreads();
    if (t < 8) {
        float mx = -3.0e38f;
#pragma unroll
        for (int m = 0; m < 8; ++m) mx = fmaxf(mx, sc[t][m]);
        float e[8], ssum = 0.f;
#pragma unroll
        for (int m = 0; m < 8; ++m) { e[m] = expf(sc[t][m] - mx); ssum += e[m]; }
        const float inv = 1.f / ssum;
#pragma unroll
        for (int m = 0; m < 8; ++m) attn[(b * 8 + t) * 8 + m] = e[m] * inv;
    }
}

// ---------------- Weff[b][co][m*48+c] = sum_n wproj[co][n*48+c]*attn[n][m]  (bf16 out)
__global__ __launch_bounds__(128) void k_weff(const float* __restrict__ attn,
                                              const float* __restrict__ wproj,
                                              u16* __restrict__ weff)
{
    const int b  = blockIdx.y;
    const int co = blockIdx.x;
    const int t  = threadIdx.x;
    __shared__ float a[64];
    if (t < 64) a[t] = attn[b * 64 + t];
    __syncthreads();
    const float* wrow = wproj + (size_t)co * DIM;
    u16* wout = weff + ((size_t)b * DIM + co) * DIM;
    for (int i = t; i < DIM; i += 128) {
        const int m = i / CPG;
        const int c = i - m * CPG;
        float s = 0.f;
#pragma unroll
        for (int n = 0; n < 8; ++n) s += wrow[n * CPG + c] * a[n * 8 + m];
        wout[i] = f2bf(s);
    }
}

extern "C" void kernel_launch(void* const* d_in, const int* in_sizes, int n_in,
                              void* d_out, int out_size, void* d_ws, size_t ws_size,
                              hipStream_t stream)
{
    const float* x      = (const float*)d_in[0];
    const float* temp   = (const float*)d_in[1];
    const float* w_qkv  = (const float*)d_in[2];
    const float* b_qkv  = (const float*)d_in[3];
    const float* w_dw   = (const float*)d_in[4];
    const float* b_dw   = (const float*)d_in[5];
    const float* w_proj = (const float*)d_in[6];
    const float* b_proj = (const float*)d_in[7];
    float* out = (float*)d_out;

    char* ws = (char*)d_ws;
    const size_t SZ_QKV = (size_t)BB * DIM3 * PP * sizeof(u16);  // 150,994,944
    const size_t SZ_XT  = (size_t)BB * PP * DIM * sizeof(u16);   //  50,331,648

    // region 0: [0, SZ_QKV) -- y1 (gemm0 out, read by k_dwv/k_dwqk, then dead)
    u16* y1 = (u16*)ws;
    u16* vt = (u16*)(ws + 4194304);               // 50.3 MB; y1 dead before tr_v

    // region 1: [SZ_QKV, 2*SZ_QKV)
    u16* y2  = (u16*)(ws + SZ_QKV);               // v channels only (>=25.2 MB in)
    u16* xt  = (u16*)(ws + SZ_QKV);               // pre-dw only (dead after gemm0)
    u16* wbf = (u16*)(ws + SZ_QKV + SZ_XT);       // 884,736 B (pre-dw only)
    // small buffers live in the xt-dead / y2-qk-unused space [0, 25 MB):
    float* partial = (float*)(ws + SZ_QKV);              // 3,145,728 B
    float* attn    = (float*)(ws + SZ_QKV + 3145728);    // 1,024 B
    u16*   weffb   = (u16*)(ws + SZ_QKV + 3211264);      // 1,179,648 B (ends ~4.4MB)

    k_wcvt<<<dim3(DIM3 * DIM / 1024), 256, 0, stream>>>(w_qkv, wbf);
    k_tr_x<<<dim3(PP / 64, DIM / 64, BB), 256, 0, stream>>>(x, xt);
    k_gemm<0><<<dim3(128 * 9 * BB), 256, 0, stream>>>(
        wbf, 0, xt, b_qkv, y1, nullptr, nullptr, 9);
    k_dwv<<<dim3(DIM, BB), 256, 0, stream>>>(y1, w_dw, b_dw, y2);
    k_dwqk<<<dim3(48, 16, BB), 256, 0, stream>>>(y1, w_dw, b_dw, partial);
    k_attn<<<dim3(BB), 256, 0, stream>>>(partial, temp, attn);
    k_weff<<<dim3(DIM, BB), 128, 0, stream>>>(attn, w_proj, weffb);
    k_tr_v<<<dim3(PP / 64, DIM / 64, BB), 256, 0, stream>>>(y2, vt);
    k_gemm<1><<<dim3(128 * 3 * BB), 256, 0, stream>>>(
        weffb, DIM * DIM, vt, b_proj, nullptr, x, out, 3);
}